// Round 9
// baseline (149.638 us; speedup 1.0000x reference)
//
#include <hip/hip_runtime.h>
#include <cmath>

#define NB 8
#define CC 256
#define NPIX 4096
#define QB 64
#define KVB 64
#define NT (NPIX / KVB)
#define LOG2E 1.4426950408889634f

typedef __attribute__((ext_vector_type(4))) float f32x4;
typedef __attribute__((ext_vector_type(8))) short s16x8;
typedef __attribute__((ext_vector_type(4))) unsigned short u16x4;
typedef __attribute__((ext_vector_type(4))) unsigned int u32x4;
typedef __attribute__((ext_vector_type(2))) unsigned int u32x2;

__device__ __forceinline__ unsigned short f2bf(float f) {
    union { float f; unsigned int u; } v; v.f = f;
    return (unsigned short)((v.u + 0x7FFFu + ((v.u >> 16) & 1u)) >> 16);
}

__device__ __forceinline__ unsigned int cvt_pk_bf16(float lo, float hi) {
    unsigned int r;
    asm("v_cvt_pk_bf16_f32 %0, %1, %2" : "=v"(r) : "v"(lo), "v"(hi));
    return r;  // low16 = bf16(lo), high16 = bf16(hi), RNE
}

__device__ __forceinline__ float u2f(unsigned int u) {
    union { unsigned int u; float f; } v; v.u = u; return v.f;
}

// ---------------------------------------------------------------------------
// proj_gemm: [Q(32);K(32);V(256)] = W · x  via MFMA, 2-term x hi/lo split.
// (unchanged — passed, ~14 µs)
// ---------------------------------------------------------------------------
__global__ __launch_bounds__(320) void proj_gemm_kernel(
    const float* __restrict__ x,
    const float* __restrict__ w1, const float* __restrict__ b1,
    const float* __restrict__ w2, const float* __restrict__ b2,
    const float* __restrict__ w3, const float* __restrict__ b3,
    unsigned short* __restrict__ Qm, unsigned short* __restrict__ Km,
    unsigned short* __restrict__ Vm)
{
    const int b  = blockIdx.x >> 6;
    const int n0 = (blockIdx.x & 63) * 64;
    const int wave = threadIdx.x >> 6;
    const int lane = threadIdx.x & 63;
    const int cl = lane & 15, g = lane >> 4;

    const float* arow[4];
#pragma unroll
    for (int ct = 0; ct < 4; ++ct) {
        const int row = wave * 64 + ct * 16 + cl;  // 0..319
        if (row < 32)       arow[ct] = w1 + (size_t)row * 256;
        else if (row < 64)  arow[ct] = w2 + (size_t)(row - 32) * 256;
        else                arow[ct] = w3 + (size_t)(row - 64) * 256;
    }

    const float* xb = x + (size_t)b * CC * NPIX + n0 + cl;

    f32x4 acc[4][4];
#pragma unroll
    for (int ct = 0; ct < 4; ++ct)
#pragma unroll
        for (int nt = 0; nt < 4; ++nt) acc[ct][nt] = (f32x4){0.f, 0.f, 0.f, 0.f};

    for (int ks = 0; ks < 8; ++ks) {
        const int c0 = ks * 32;
        s16x8 ah[4];
#pragma unroll
        for (int ct = 0; ct < 4; ++ct) {
            const float* ap = arow[ct] + c0 + g * 8;
            f32x4 a0 = *(const f32x4*)ap;
            f32x4 a1 = *(const f32x4*)(ap + 4);
            u32x4 u;
            u[0] = cvt_pk_bf16(a0[0], a0[1]); u[1] = cvt_pk_bf16(a0[2], a0[3]);
            u[2] = cvt_pk_bf16(a1[0], a1[1]); u[3] = cvt_pk_bf16(a1[2], a1[3]);
            ah[ct] = __builtin_bit_cast(s16x8, u);
        }
#pragma unroll
        for (int nt = 0; nt < 4; ++nt) {
            const float* xp = xb + (size_t)(c0 + g * 8) * NPIX + nt * 16;
            float xe[8];
#pragma unroll
            for (int e = 0; e < 8; ++e) xe[e] = xp[(size_t)e * NPIX];
            u32x4 uh, ul;
#pragma unroll
            for (int p = 0; p < 4; ++p) {
                const unsigned int hp = cvt_pk_bf16(xe[2 * p], xe[2 * p + 1]);
                const float h0 = u2f(hp << 16);
                const float h1 = u2f(hp & 0xffff0000u);
                uh[p] = hp;
                ul[p] = cvt_pk_bf16(xe[2 * p] - h0, xe[2 * p + 1] - h1);
            }
            const s16x8 bh = __builtin_bit_cast(s16x8, uh);
            const s16x8 bl = __builtin_bit_cast(s16x8, ul);
#pragma unroll
            for (int ct = 0; ct < 4; ++ct)
                acc[ct][nt] = __builtin_amdgcn_mfma_f32_16x16x32_bf16(ah[ct], bh, acc[ct][nt], 0, 0, 0);
#pragma unroll
            for (int ct = 0; ct < 4; ++ct)
                acc[ct][nt] = __builtin_amdgcn_mfma_f32_16x16x32_bf16(ah[ct], bl, acc[ct][nt], 0, 0, 0);
        }
    }

    if (wave == 0) {
#pragma unroll
        for (int ct = 0; ct < 4; ++ct) {
#pragma unroll
            for (int nt = 0; nt < 4; ++nt) {
                const int n = n0 + nt * 16 + cl;
                const int co = ct * 16 + g * 4;
                f32x4 v = acc[ct][nt];
                if (ct < 2) {  // Q, pre-scaled by log2e
                    const float q0 = (v[0] + b1[co + 0]) * LOG2E;
                    const float q1 = (v[1] + b1[co + 1]) * LOG2E;
                    const float q2 = (v[2] + b1[co + 2]) * LOG2E;
                    const float q3 = (v[3] + b1[co + 3]) * LOG2E;
                    u32x2 dd = {cvt_pk_bf16(q0, q1), cvt_pk_bf16(q2, q3)};
                    *(u32x2*)(Qm + ((size_t)b * NPIX + n) * 32 + co) = dd;
                } else {
                    const int ko = co - 32;
                    const float k0 = v[0] + b2[ko + 0];
                    const float k1 = v[1] + b2[ko + 1];
                    const float k2 = v[2] + b2[ko + 2];
                    const float k3 = v[3] + b2[ko + 3];
                    u32x2 dd = {cvt_pk_bf16(k0, k1), cvt_pk_bf16(k2, k3)};
                    *(u32x2*)(Km + ((size_t)b * NPIX + n) * 32 + ko) = dd;
                }
            }
        }
    } else {
        const int cvb = (wave - 1) * 64;
#pragma unroll
        for (int ct = 0; ct < 4; ++ct) {
#pragma unroll
            for (int nt = 0; nt < 4; ++nt) {
                const int n = n0 + nt * 16 + cl;
                const int cv = cvb + ct * 16 + g * 4;
#pragma unroll
                for (int r = 0; r < 4; ++r)
                    Vm[((size_t)b * CC + cv + r) * NPIX + n] = f2bf(acc[ct][nt][r] + b3[cv + r]);
            }
        }
    }
}

// ---------------------------------------------------------------------------
// attn v8: pipelined softmax (T15). 512 threads / 8 waves, 2 blocks/CU.
// Waves 0-3 (owners): softmax for q-slice + 16-channel PV slice.
// Waves 4-7: 48-channel PV slice. Same total MFMA; paths balanced.
// In iter t owners compute QK/softmax for tile t+1 (into Ps[(t+1)&1]) while
// non-owners run PV(t) -> softmax VALU overlaps PV MFMA.
// Barrier audit: Ps/alpha[(t+1)&1] written after B(t), read after B(t+1);
// Vs committed after A(t), read after B(t), prior reads end before A(t+1).
// ---------------------------------------------------------------------------
__global__ __launch_bounds__(512, 4) void attn_kernel(
    const unsigned short* __restrict__ Qm, const unsigned short* __restrict__ Km,
    const unsigned short* __restrict__ Vm, const float* __restrict__ gamma,
    float* __restrict__ out)
{
    __shared__ unsigned short Vs[CC * KVB];     // [c][m] 32KB, swizzled, single
    __shared__ unsigned short Ps[2][QB * KVB];  // [q][m] 2x8KB, swizzled
    __shared__ float alpha_lds[2][QB];          // per-q rescale factor
    __shared__ float l_lds[QB];                 // final denominators

    // XCD swizzle: each XCD gets one batch's 64 q-blocks (K+V fit its 4MB L2)
    const int bid = ((blockIdx.x & 7) << 6) + (blockIdx.x >> 3);
    const int b = bid >> 6;
    const int q0 = (bid & 63) * QB;

    const int t = threadIdx.x;
    const int wave = t >> 6;
    const int lane = t & 63;
    const int cl = lane & 15;
    const int g = lane >> 4;
    const bool owner = wave < 4;                     // softmax owner waves
    const int c0w = owner ? (wave * 16) : (64 + (wave - 4) * 48);
    const int NCT = owner ? 1 : 3;                   // PV channel sub-tiles
    const int qrow_own = (wave & 3) * 16 + cl;       // owned q-row (waves 0-3)

    // Q B-frag for the owned q-slice: B[k=d][col=q]
    const s16x8 qf = *(const s16x8*)(Qm + (((size_t)b * NPIX) + q0 + qrow_own) * 32 + g * 8);

    f32x4 acc[4][3];  // [qt][ct]: q = qt*16+cl, c = c0w + ct*16 + g*4 + r
#pragma unroll
    for (int qt = 0; qt < 4; ++qt)
#pragma unroll
        for (int ct = 0; ct < 3; ++ct)
            acc[qt][ct] = (f32x4){0.f, 0.f, 0.f, 0.f};

    float mrun = -__builtin_inff();
    float lrun = 0.f;  // per-lane partial; g-reduced once in epilogue

    const unsigned short* Kg = Km + (size_t)b * NPIX * 32;
    const unsigned short* Vg = Vm + (size_t)b * CC * NPIX;

    // V staging: 512 threads, 8 chunks/row -> 64 rows/pass, 4 passes
    const int vin = t & 7;
    const int vr0 = t >> 3;  // 0..63; (vr0 + i*64)&7 == vr0&7
    const unsigned short* vsrc = Vg + (size_t)vr0 * NPIX + vin * 8;
    unsigned short* vdst = &Vs[vr0 * 64 + ((vin ^ (vr0 & 7)) << 3)];

    // ---- prologue -----------------------------------------------------------
    // V tile 0 into regs
    s16x8 vreg[4];
#pragma unroll
    for (int i = 0; i < 4; ++i)
        vreg[i] = *(const s16x8*)(vsrc + (size_t)i * 64 * NPIX);

    // K frags for tile 0 -> QK(0) + softmax(0) -> Ps[0], alpha[0]; then kf(1)
    s16x8 kf[4];
    if (owner) {
#pragma unroll
        for (int mt = 0; mt < 4; ++mt)
            kf[mt] = *(const s16x8*)(Kg + (size_t)(mt * 16 + cl) * 32 + g * 8);

        f32x4 s[4];
#pragma unroll
        for (int mt = 0; mt < 4; ++mt) {
            f32x4 z = (f32x4){0.f, 0.f, 0.f, 0.f};
            s[mt] = __builtin_amdgcn_mfma_f32_16x16x32_bf16(kf[mt], qf, z, 0, 0, 0);
        }
        float ml = -__builtin_inff();
#pragma unroll
        for (int mt = 0; mt < 4; ++mt)
#pragma unroll
            for (int r = 0; r < 4; ++r) ml = fmaxf(ml, s[mt][r]);
        ml = fmaxf(ml, __shfl_xor(ml, 16, 64));
        ml = fmaxf(ml, __shfl_xor(ml, 32, 64));
        mrun = ml;
        if (g == 0) alpha_lds[0][qrow_own] = 1.f;
#pragma unroll
        for (int mt = 0; mt < 4; ++mt) {
#pragma unroll
            for (int r = 0; r < 4; ++r) {
                s[mt][r] = __builtin_amdgcn_exp2f(s[mt][r] - mrun);
                lrun += s[mt][r];
            }
        }
#pragma unroll
        for (int mt = 0; mt < 4; ++mt) {
            u32x2 dd = {cvt_pk_bf16(s[mt][0], s[mt][1]),
                        cvt_pk_bf16(s[mt][2], s[mt][3])};
            *(u32x2*)(&Ps[0][qrow_own * 64 + ((mt * 16 + g * 4) ^ ((qrow_own & 7) << 3))]) = dd;
        }
        // prefetch kf for tile 1
#pragma unroll
        for (int mt = 0; mt < 4; ++mt)
            kf[mt] = *(const s16x8*)(Kg + (size_t)(KVB + mt * 16 + cl) * 32 + g * 8);
    }

    // ---- main loop ----------------------------------------------------------
    for (int it = 0; it < NT; ++it) {
        const int buf = it & 1;

        __syncthreads();  // A: prev PV's Vs/Ps reads complete

        // commit prefetched V tile to LDS; issue next tile's loads (wrap)
#pragma unroll
        for (int i = 0; i < 4; ++i)
            *(s16x8*)(vdst + i * 64 * 64) = vreg[i];
        {
            const int mn = ((it + 1) & (NT - 1)) * KVB;
#pragma unroll
            for (int i = 0; i < 4; ++i)
                vreg[i] = *(const s16x8*)(vsrc + (size_t)i * 64 * NPIX + mn);
        }

        __syncthreads();  // B: Vs(t) ready; Ps[buf]/alpha[buf] ready (from t-1)

        // rescale acc by per-q alpha (rare thanks to defer-max)
        float aq[4];
#pragma unroll
        for (int qt = 0; qt < 4; ++qt) aq[qt] = alpha_lds[buf][qt * 16 + cl];
        if (__any(aq[0] != 1.f || aq[1] != 1.f || aq[2] != 1.f || aq[3] != 1.f)) {
#pragma unroll
            for (int qt = 0; qt < 4; ++qt)
#pragma unroll
                for (int ct = 0; ct < 3; ++ct) acc[qt][ct] *= aq[qt];
        }

        // owners: QK + softmax for tile t+1 (overlaps non-owner PV below)
        if (owner && it < NT - 1) {
            f32x4 s[4];
            __builtin_amdgcn_s_setprio(1);
#pragma unroll
            for (int mt = 0; mt < 4; ++mt) {
                f32x4 z = (f32x4){0.f, 0.f, 0.f, 0.f};
                s[mt] = __builtin_amdgcn_mfma_f32_16x16x32_bf16(kf[mt], qf, z, 0, 0, 0);
            }
            __builtin_amdgcn_s_setprio(0);

            float ml = -__builtin_inff();
#pragma unroll
            for (int mt = 0; mt < 4; ++mt)
#pragma unroll
                for (int r = 0; r < 4; ++r) ml = fmaxf(ml, s[mt][r]);
            ml = fmaxf(ml, __shfl_xor(ml, 16, 64));
            ml = fmaxf(ml, __shfl_xor(ml, 32, 64));

            float alpha = 1.f;
            if (!__all(ml <= mrun + 8.f)) {  // defer-max (T13)
                const float mnew = fmaxf(mrun, ml);
                alpha = __builtin_amdgcn_exp2f(mrun - mnew);
                mrun = mnew;
                lrun *= alpha;
            }
            if (g == 0) alpha_lds[buf ^ 1][qrow_own] = alpha;

#pragma unroll
            for (int mt = 0; mt < 4; ++mt) {
#pragma unroll
                for (int r = 0; r < 4; ++r) {
                    s[mt][r] = __builtin_amdgcn_exp2f(s[mt][r] - mrun);
                    lrun += s[mt][r];
                }
            }
#pragma unroll
            for (int mt = 0; mt < 4; ++mt) {
                u32x2 dd = {cvt_pk_bf16(s[mt][0], s[mt][1]),
                            cvt_pk_bf16(s[mt][2], s[mt][3])};
                *(u32x2*)(&Ps[buf ^ 1][qrow_own * 64 + ((mt * 16 + g * 4) ^ ((qrow_own & 7) << 3))]) = dd;
            }

            // prefetch kf for tile t+2 (wrap; in-bounds, possibly unused)
            const int mnext = ((it + 2) & (NT - 1)) * KVB;
#pragma unroll
            for (int mt = 0; mt < 4; ++mt)
                kf[mt] = *(const s16x8*)(Kg + (size_t)(mnext + mt * 16 + cl) * 32 + g * 8);
        }

        // PV(t): acc[qt][ct] += mfma(A=V[c][m] (LDS), B=P^T[m][q] (LDS))
#pragma unroll
        for (int ch = 0; ch < 2; ++ch) {
            s16x8 pb[4];
#pragma unroll
            for (int qt = 0; qt < 4; ++qt) {
                const int qr = qt * 16 + cl;
                pb[qt] = *(const s16x8*)(&Ps[buf][qr * 64 + ((ch * 32 + g * 8) ^ ((qr & 7) << 3))]);
            }
            __builtin_amdgcn_s_setprio(1);
#pragma unroll
            for (int ct = 0; ct < 3; ++ct) {
                if (ct < NCT) {
                    const int cr = c0w + ct * 16 + cl;
                    s16x8 av = *(const s16x8*)(&Vs[cr * 64 + ((ch * 32 + g * 8) ^ ((cr & 7) << 3))]);
#pragma unroll
                    for (int qt = 0; qt < 4; ++qt)
                        acc[qt][ct] = __builtin_amdgcn_mfma_f32_16x16x32_bf16(av, pb[qt], acc[qt][ct], 0, 0, 0);
                }
            }
            __builtin_amdgcn_s_setprio(0);
        }
    }

    // epilogue: owners reduce lrun over g-groups, share denominators
    if (owner) {
        lrun += __shfl_xor(lrun, 16, 64);
        lrun += __shfl_xor(lrun, 32, 64);
        if (g == 0) l_lds[qrow_own] = lrun;
    }
    __syncthreads();

    // coalesced [b][c][n] stores; second output = gamma*val
    const float gm = gamma[0];
    float* out2 = out + (size_t)NB * CC * NPIX;
#pragma unroll
    for (int qt = 0; qt < 4; ++qt) {
        const float inv = 1.f / l_lds[qt * 16 + cl];
        const int n = q0 + qt * 16 + cl;
#pragma unroll
        for (int ct = 0; ct < 3; ++ct) {
            if (ct < NCT) {
#pragma unroll
                for (int r = 0; r < 4; ++r) {
                    const int chn = c0w + ct * 16 + g * 4 + r;
                    const float val = acc[qt][ct][r] * inv;
                    const size_t idx = ((size_t)b * CC + chn) * NPIX + n;
                    out[idx] = val;
                    out2[idx] = gm * val;
                }
            }
        }
    }
}

// ---------------------------------------------------------------------------
extern "C" void kernel_launch(void* const* d_in, const int* in_sizes, int n_in,
                              void* d_out, int out_size, void* d_ws, size_t ws_size,
                              hipStream_t stream) {
    (void)in_sizes; (void)n_in; (void)out_size; (void)ws_size;
    const float* x     = (const float*)d_in[0];
    const float* w1    = (const float*)d_in[1];
    const float* b1    = (const float*)d_in[2];
    const float* w2    = (const float*)d_in[3];
    const float* b2    = (const float*)d_in[4];
    const float* w3    = (const float*)d_in[5];
    const float* b3    = (const float*)d_in[6];
    const float* gamma = (const float*)d_in[7];
    float* out = (float*)d_out;

    unsigned short* Qm = (unsigned short*)d_ws;                       // 2 MB
    unsigned short* Km = Qm + (size_t)NB * NPIX * 32;                 // 2 MB
    unsigned short* Vm = Km + (size_t)NB * NPIX * 32;                 // 16 MB

    proj_gemm_kernel<<<NB * 64, 320, 0, stream>>>(x, w1, b1, w2, b2, w3, b3, Qm, Km, Vm);
    attn_kernel<<<NB * 64, 512, 0, stream>>>(Qm, Km, Vm, gamma, out);
}